// Round 1
// 425.326 us; speedup vs baseline: 1.0187x; 1.0187x over previous
//
#include <hip/hip_runtime.h>

// 3-level 2D Haar DWT, x: (16, 64, 256, 256) fp32.
// No padding occurs (all dims even). Stride-2 filt-2 => non-overlapping 2x2
// blocks, zero halo: fully fused, register-only, no LDS.
//
// R4: remap lanes so EVERY global instruction is wave-contiguous.
//     Lane l owns cols [4l,4l+4) (one dwordx4 = 1KiB/wave contiguous, each
//     64B line fetched exactly once by exactly one nt load -> no reliance on
//     L2 covering the second half of a 32B-strided pair).
//     Wave w (tid>>6) owns 16 rows of the 64-row strip.
//     L1 stores: v2f (512B/instr contiguous). L2: dword (256B/instr).
//     L3: horizontal LL2 neighbor fetched via __shfl_xor(1); even lanes store.
//
// Output concat order: l3, lh3, hl3, hh3, lh2, hl2, hh2, lh1, hl1, hh1

#define S3       1048576       // 1024*32*32
#define S2       4194304       // 1024*64*64
#define S1       16777216      // 1024*128*128

typedef float v4f __attribute__((ext_vector_type(4)));
typedef float v2f __attribute__((ext_vector_type(2)));

__device__ __forceinline__ v4f ntload4(const float* p) {
    return __builtin_nontemporal_load((const v4f*)p);
}
__device__ __forceinline__ void ntstore2(float* p, v2f v) {
    __builtin_nontemporal_store(v, (v2f*)p);
}
__device__ __forceinline__ void ntstore1(float* p, float v) {
    __builtin_nontemporal_store(v, p);
}

__global__ __launch_bounds__(256) void dwt3_haar_r4(const float* __restrict__ x,
                                                    float* __restrict__ out) {
    const int bid = blockIdx.x;
    const int p   = bid >> 2;     // plane index (b*64+c)
    const int s   = bid & 3;      // 64-row strip within plane
    const int tid = threadIdx.x;
    const int l   = tid & 63;     // lane: cols [4l, 4l+4)
    const int w   = tid >> 6;     // wave: rows [16w, 16w+16) within strip

    const float* in = x + (size_t)p * 65536
                        + (size_t)(64 * s + 16 * w) * 256
                        + (size_t)(4 * l);

    float* __restrict__ l3  = out;
    float* __restrict__ lh3 = out + (size_t)S3;
    float* __restrict__ hl3 = out + (size_t)2 * S3;
    float* __restrict__ hh3 = out + (size_t)3 * S3;
    float* __restrict__ lh2 = out + (size_t)4 * S3;
    float* __restrict__ hl2 = out + (size_t)4 * S3 + S2;
    float* __restrict__ hh2 = out + (size_t)4 * S3 + 2 * (size_t)S2;
    float* __restrict__ lh1 = out + (size_t)4 * S3 + 3 * (size_t)S2;
    float* __restrict__ hl1 = out + (size_t)4 * S3 + 3 * (size_t)S2 + (size_t)S1;
    float* __restrict__ hh1 = out + (size_t)4 * S3 + 3 * (size_t)S2 + 2 * (size_t)S1;

    // ---- Issue ALL global loads up front: 16 outstanding dwordx4 / thread,
    //      each instruction a fully-contiguous 1KiB wave segment ----
    v4f row[16];
#pragma unroll
    for (int r = 0; r < 16; ++r)
        row[r] = ntload4(in + (size_t)r * 256);

    // ---- Level 1: 16x4 input patch -> 8x2 per subband (128x128 planes) ----
    float ll1[8][2];
#pragma unroll
    for (int rp = 0; rp < 8; ++rp) {
        const v4f t = row[2 * rp];
        const v4f u = row[2 * rp + 1];
        float lhv[2], hlv[2], hhv[2];
#pragma unroll
        for (int j = 0; j < 2; ++j) {
            const float a = t[2 * j], b = t[2 * j + 1];
            const float c = u[2 * j], d = u[2 * j + 1];
            const float s1 = a + b, s2 = c + d;
            const float d1 = a - b, d2 = c - d;
            ll1[rp][j] = 0.5f * (s1 + s2);
            lhv[j]     = 0.5f * (s1 - s2);
            hlv[j]     = 0.5f * (d1 + d2);
            hhv[j]     = 0.5f * (d1 - d2);
        }
        const size_t o1 = (size_t)p * 16384
                        + (size_t)(32 * s + 8 * w + rp) * 128
                        + (size_t)(2 * l);
        ntstore2(lh1 + o1, (v2f){lhv[0], lhv[1]});
        ntstore2(hl1 + o1, (v2f){hlv[0], hlv[1]});
        ntstore2(hh1 + o1, (v2f){hhv[0], hhv[1]});
    }

    // ---- Level 2: 8x2 LL1 -> 4x1 per subband (64x64 planes) ----
    float ll2[4];
#pragma unroll
    for (int rp = 0; rp < 4; ++rp) {
        const float a = ll1[2 * rp][0],     b = ll1[2 * rp][1];
        const float c = ll1[2 * rp + 1][0], d = ll1[2 * rp + 1][1];
        const float s1 = a + b, s2 = c + d;
        const float d1 = a - b, d2 = c - d;
        ll2[rp] = 0.5f * (s1 + s2);
        const size_t o2 = (size_t)p * 4096
                        + (size_t)(16 * s + 4 * w + rp) * 64
                        + (size_t)l;
        ntstore1(lh2 + o2, 0.5f * (s1 - s2));
        ntstore1(hl2 + o2, 0.5f * (d1 + d2));
        ntstore1(hh2 + o2, 0.5f * (d1 - d2));
    }

    // ---- Level 3: 4x1 LL2 (col l) + neighbor col (lane l^1) -> 2 outputs
    //      at col l>>1 (32x32 planes). Even lanes store. ----
#pragma unroll
    for (int q = 0; q < 2; ++q) {
        const float own0 = ll2[2 * q];
        const float own1 = ll2[2 * q + 1];
        const float par0 = __shfl_xor(own0, 1);
        const float par1 = __shfl_xor(own1, 1);
        // On even lanes: own = left col (a,c), partner = right col (b,d).
        const float s1 = own0 + par0, s2 = own1 + par1;
        const float d1 = own0 - par0, d2 = own1 - par1;
        if ((l & 1) == 0) {
            const size_t o3 = (size_t)p * 1024
                            + (size_t)(8 * s + 2 * w + q) * 32
                            + (size_t)(l >> 1);
            ntstore1(l3  + o3, 0.5f * (s1 + s2));
            ntstore1(lh3 + o3, 0.5f * (s1 - s2));
            ntstore1(hl3 + o3, 0.5f * (d1 + d2));
            ntstore1(hh3 + o3, 0.5f * (d1 - d2));
        }
    }
}

extern "C" void kernel_launch(void* const* d_in, const int* in_sizes, int n_in,
                              void* d_out, int out_size, void* d_ws, size_t ws_size,
                              hipStream_t stream) {
    const float* x = (const float*)d_in[0];
    float* out = (float*)d_out;
    // 1024 planes * 4 strips = 4096 blocks, 256 threads each
    dwt3_haar_r4<<<4096, 256, 0, stream>>>(x, out);
}

// Round 2
// 423.451 us; speedup vs baseline: 1.0232x; 1.0044x over previous
//
#include <hip/hip_runtime.h>

// 3-level 2D Haar DWT, x: (16, 64, 256, 256) fp32.
// No padding occurs (all dims even). Stride-2 filt-2 => non-overlapping 2x2
// blocks, zero halo: fully fused, register-only, no LDS.
//
// R5: occupancy push. 8 rows/thread (was 16) -> row[8]=32 VGPR,
//     __launch_bounds__(256,6) caps VGPR ~85 -> 6 waves/SIMD (was ~4).
//     8192 blocks x 32-row strips. All global instructions remain fully
//     wave-contiguous (lane l owns cols [4l,4l+4)); bytes moved unchanged.
//
// Output concat order: l3, lh3, hl3, hh3, lh2, hl2, hh2, lh1, hl1, hh1

#define S3       1048576       // 1024*32*32
#define S2       4194304       // 1024*64*64
#define S1       16777216      // 1024*128*128

typedef float v4f __attribute__((ext_vector_type(4)));
typedef float v2f __attribute__((ext_vector_type(2)));

__device__ __forceinline__ v4f ntload4(const float* p) {
    return __builtin_nontemporal_load((const v4f*)p);
}
__device__ __forceinline__ void ntstore2(float* p, v2f v) {
    __builtin_nontemporal_store(v, (v2f*)p);
}
__device__ __forceinline__ void ntstore1(float* p, float v) {
    __builtin_nontemporal_store(v, p);
}

__global__ __launch_bounds__(256, 6) void dwt3_haar_r5(const float* __restrict__ x,
                                                       float* __restrict__ out) {
    const int bid = blockIdx.x;
    const int p   = bid >> 3;     // plane index (b*64+c)
    const int s   = bid & 7;      // 32-row strip within plane
    const int tid = threadIdx.x;
    const int l   = tid & 63;     // lane: cols [4l, 4l+4)
    const int w   = tid >> 6;     // wave: rows [8w, 8w+8) within strip

    const float* in = x + (size_t)p * 65536
                        + (size_t)(32 * s + 8 * w) * 256
                        + (size_t)(4 * l);

    float* __restrict__ l3  = out;
    float* __restrict__ lh3 = out + (size_t)S3;
    float* __restrict__ hl3 = out + (size_t)2 * S3;
    float* __restrict__ hh3 = out + (size_t)3 * S3;
    float* __restrict__ lh2 = out + (size_t)4 * S3;
    float* __restrict__ hl2 = out + (size_t)4 * S3 + S2;
    float* __restrict__ hh2 = out + (size_t)4 * S3 + 2 * (size_t)S2;
    float* __restrict__ lh1 = out + (size_t)4 * S3 + 3 * (size_t)S2;
    float* __restrict__ hl1 = out + (size_t)4 * S3 + 3 * (size_t)S2 + (size_t)S1;
    float* __restrict__ hh1 = out + (size_t)4 * S3 + 3 * (size_t)S2 + 2 * (size_t)S1;

    // ---- Issue ALL global loads up front: 8 outstanding dwordx4 / thread,
    //      each instruction a fully-contiguous 1KiB wave segment ----
    v4f row[8];
#pragma unroll
    for (int r = 0; r < 8; ++r)
        row[r] = ntload4(in + (size_t)r * 256);

    // ---- Level 1: 8x4 input patch -> 4x2 per subband (128x128 planes) ----
    float ll1[4][2];
#pragma unroll
    for (int rp = 0; rp < 4; ++rp) {
        const v4f t = row[2 * rp];
        const v4f u = row[2 * rp + 1];
        float lhv[2], hlv[2], hhv[2];
#pragma unroll
        for (int j = 0; j < 2; ++j) {
            const float a = t[2 * j], b = t[2 * j + 1];
            const float c = u[2 * j], d = u[2 * j + 1];
            const float s1 = a + b, s2 = c + d;
            const float d1 = a - b, d2 = c - d;
            ll1[rp][j] = 0.5f * (s1 + s2);
            lhv[j]     = 0.5f * (s1 - s2);
            hlv[j]     = 0.5f * (d1 + d2);
            hhv[j]     = 0.5f * (d1 - d2);
        }
        const size_t o1 = (size_t)p * 16384
                        + (size_t)(16 * s + 4 * w + rp) * 128
                        + (size_t)(2 * l);
        ntstore2(lh1 + o1, (v2f){lhv[0], lhv[1]});
        ntstore2(hl1 + o1, (v2f){hlv[0], hlv[1]});
        ntstore2(hh1 + o1, (v2f){hhv[0], hhv[1]});
    }

    // ---- Level 2: 4x2 LL1 -> 2x1 per subband (64x64 planes) ----
    float ll2[2];
#pragma unroll
    for (int rp = 0; rp < 2; ++rp) {
        const float a = ll1[2 * rp][0],     b = ll1[2 * rp][1];
        const float c = ll1[2 * rp + 1][0], d = ll1[2 * rp + 1][1];
        const float s1 = a + b, s2 = c + d;
        const float d1 = a - b, d2 = c - d;
        ll2[rp] = 0.5f * (s1 + s2);
        const size_t o2 = (size_t)p * 4096
                        + (size_t)(8 * s + 2 * w + rp) * 64
                        + (size_t)l;
        ntstore1(lh2 + o2, 0.5f * (s1 - s2));
        ntstore1(hl2 + o2, 0.5f * (d1 + d2));
        ntstore1(hh2 + o2, 0.5f * (d1 - d2));
    }

    // ---- Level 3: 2x1 LL2 (col l) + neighbor col (lane l^1) -> 1 output
    //      at col l>>1 (32x32 planes). Even lanes store. ----
    {
        const float own0 = ll2[0];
        const float own1 = ll2[1];
        const float par0 = __shfl_xor(own0, 1);
        const float par1 = __shfl_xor(own1, 1);
        // On even lanes: own = left col (a,c), partner = right col (b,d).
        const float s1 = own0 + par0, s2 = own1 + par1;
        const float d1 = own0 - par0, d2 = own1 - par1;
        if ((l & 1) == 0) {
            const size_t o3 = (size_t)p * 1024
                            + (size_t)(4 * s + w) * 32
                            + (size_t)(l >> 1);
            ntstore1(l3  + o3, 0.5f * (s1 + s2));
            ntstore1(lh3 + o3, 0.5f * (s1 - s2));
            ntstore1(hl3 + o3, 0.5f * (d1 + d2));
            ntstore1(hh3 + o3, 0.5f * (d1 - d2));
        }
    }
}

extern "C" void kernel_launch(void* const* d_in, const int* in_sizes, int n_in,
                              void* d_out, int out_size, void* d_ws, size_t ws_size,
                              hipStream_t stream) {
    const float* x = (const float*)d_in[0];
    float* out = (float*)d_out;
    // 1024 planes * 8 strips = 8192 blocks, 256 threads each
    dwt3_haar_r5<<<8192, 256, 0, stream>>>(x, out);
}